// Round 1
// baseline (16892.976 us; speedup 1.0000x reference)
//
#include <hip/hip_runtime.h>

#define NN 100000
#define NE 600000
#define DD 128
#define NL 16

__global__ void k_deg(const int* __restrict__ ei, float* __restrict__ deg) {
    int e = blockIdx.x * blockDim.x + threadIdx.x;
    if (e < NE) atomicAdd(&deg[ei[e]], 1.0f);
}

__global__ void k_vals(const int* __restrict__ ei, const float* __restrict__ deg,
                       float* __restrict__ vals) {
    int e = blockIdx.x * blockDim.x + threadIdx.x;
    if (e >= NE) return;
    int r = ei[e], c = ei[NE + e];
    float dr = deg[r], dc = deg[c];
    float ir = dr > 0.f ? rsqrtf(dr) : 0.f;
    float ic = dc > 0.f ? rsqrtf(dc) : 0.f;
    vals[e] = ir * ic;
}

// y[row[e]] += vals[e] * x[col[e]]  (32 threads per edge, float4 each)
__global__ void k_spmm(const int* __restrict__ ei, const float* __restrict__ vals,
                       const float* __restrict__ x, float* __restrict__ y) {
    long long tid = (long long)blockIdx.x * blockDim.x + threadIdx.x;
    int e = (int)(tid >> 5);
    if (e >= NE) return;
    int d4 = ((int)tid & 31) << 2;
    int r = ei[e], c = ei[NE + e];
    float v = vals[e];
    const float4 xv = *reinterpret_cast<const float4*>(x + (size_t)c * DD + d4);
    float* yp = y + (size_t)r * DD + d4;
    atomicAdd(yp + 0, v * xv.x);
    atomicAdd(yp + 1, v * xv.y);
    atomicAdd(yp + 2, v * xv.z);
    atomicAdd(yp + 3, v * xv.w);
}

// acc[nr] += coef * x[nc] over the 120 mirrored negative edges of this layer
__global__ void k_neg(const int* __restrict__ nl, const float* __restrict__ x,
                      float* __restrict__ acc, float coef) {
    int tid = blockIdx.x * blockDim.x + threadIdx.x;
    int e = tid >> 5;
    if (e >= 120) return;
    int d4 = (tid & 31) << 2;
    int r = nl[e];
    int c = (e < 60) ? nl[60 + e] : nl[e - 60];
    const float4 xv = *reinterpret_cast<const float4*>(x + (size_t)c * DD + d4);
    float* ap = acc + (size_t)r * DD + d4;
    atomicAdd(ap + 0, coef * xv.x);
    atomicAdd(ap + 1, coef * xv.y);
    atomicAdd(ap + 2, coef * xv.z);
    atomicAdd(ap + 3, coef * xv.w);
}

// x_new = (1-b)*x_old + b*y ; acc += 0.5*x_new + 0.5*al*x_old
__global__ void k_pointwise(const float* __restrict__ xo, float* __restrict__ xn,
                            float* __restrict__ acc, float b, float al) {
    size_t i = ((size_t)blockIdx.x * blockDim.x + threadIdx.x) * 4;
    if (i >= (size_t)NN * DD) return;
    float4 o = *reinterpret_cast<const float4*>(xo + i);
    float4 y = *reinterpret_cast<float4*>(xn + i);
    float4 a = *reinterpret_cast<float4*>(acc + i);
    float4 n;
    n.x = (1.f - b) * o.x + b * y.x;
    n.y = (1.f - b) * o.y + b * y.y;
    n.z = (1.f - b) * o.z + b * y.z;
    n.w = (1.f - b) * o.w + b * y.w;
    a.x += 0.5f * n.x + 0.5f * al * o.x;
    a.y += 0.5f * n.y + 0.5f * al * o.y;
    a.z += 0.5f * n.z + 0.5f * al * o.z;
    a.w += 0.5f * n.w + 0.5f * al * o.w;
    *reinterpret_cast<float4*>(xn + i) = n;
    *reinterpret_cast<float4*>(acc + i) = a;
}

// out = ALPHA*feat + ((1-ALPHA)/16)*acc   (acc lives in out)
__global__ void k_final(const float* __restrict__ feat, float* __restrict__ out) {
    size_t i = ((size_t)blockIdx.x * blockDim.x + threadIdx.x) * 4;
    if (i >= (size_t)NN * DD) return;
    float4 f = *reinterpret_cast<const float4*>(feat + i);
    float4 a = *reinterpret_cast<float4*>(out + i);
    float4 o;
    const float s = 0.85f / 16.f;
    o.x = 0.15f * f.x + s * a.x;
    o.y = 0.15f * f.y + s * a.y;
    o.z = 0.15f * f.z + s * a.z;
    o.w = 0.15f * f.w + s * a.w;
    *reinterpret_cast<float4*>(out + i) = o;
}

extern "C" void kernel_launch(void* const* d_in, const int* in_sizes, int n_in,
                              void* d_out, int out_size, void* d_ws, size_t ws_size,
                              hipStream_t stream) {
    const float* feat = (const float*)d_in[0];
    const int* ei = (const int*)d_in[1];
    const int* negei = (const int*)d_in[2];
    float* out = (float*)d_out;

    float* x0 = (float*)d_ws;                       // NN*DD
    float* x1 = x0 + (size_t)NN * DD;               // NN*DD
    float* vals = x1 + (size_t)NN * DD;             // NE
    float* deg = vals + NE;                         // NN

    const size_t xbytes = (size_t)NN * DD * sizeof(float);

    hipMemsetAsync(deg, 0, NN * sizeof(float), stream);
    hipMemsetAsync(out, 0, xbytes, stream);
    hipMemcpyAsync(x0, feat, xbytes, hipMemcpyDeviceToDevice, stream);

    k_deg<<<(NE + 255) / 256, 256, 0, stream>>>(ei, deg);
    k_vals<<<(NE + 255) / 256, 256, 0, stream>>>(ei, deg, vals);

    const double c = 120.0 / 100000.0 + 2.0;
    double b = 1.0, bn = 1.0;
    float* xo = x0;
    float* xn = x1;
    const int pw_blocks = ((NN * DD / 4) + 255) / 256;
    for (int l = 0; l < NL; ++l) {
        hipMemsetAsync(xn, 0, xbytes, stream);
        k_spmm<<<((size_t)NE * 32 + 255) / 256, 256, 0, stream>>>(ei, vals, xo, xn);
        float negcoef = (float)(-0.5 * bn / c);
        k_neg<<<(120 * 32 + 255) / 256, 256, 0, stream>>>(negei + l * 120, xo, out, negcoef);
        float al = (float)((1.0 - bn) + 2.0 * bn / c);
        k_pointwise<<<pw_blocks, 256, 0, stream>>>(xo, xn, out, (float)b, al);
        float* t = xo; xo = xn; xn = t;
        b *= 0.9; bn *= 0.5;
    }
    k_final<<<pw_blocks, 256, 0, stream>>>(feat, out);
}

// Round 2
// 1650.987 us; speedup vs baseline: 10.2320x; 10.2320x over previous
//
#include <hip/hip_runtime.h>

#define NN 100000
#define NE 600000
#define DD 128
#define NL 16

// --- CSR build ---------------------------------------------------------------

__global__ void k_deg(const int* __restrict__ ei, int* __restrict__ deg) {
    int e = blockIdx.x * blockDim.x + threadIdx.x;
    if (e < NE) atomicAdd(&deg[ei[e]], 1);
}

__global__ void k_dis(const int* __restrict__ deg, float* __restrict__ dis) {
    int i = blockIdx.x * blockDim.x + threadIdx.x;
    if (i >= NN) return;
    int d = deg[i];
    dis[i] = d > 0 ? rsqrtf((float)d) : 0.f;
}

// single-block chunked inclusive scan -> exclusive rowptr
__global__ void k_scan(const int* __restrict__ cnt, int* __restrict__ rowptr) {
    __shared__ int sh[1024];
    __shared__ int carry;
    if (threadIdx.x == 0) carry = 0;
    __syncthreads();
    for (int base = 0; base < NN; base += 1024) {
        int i = base + threadIdx.x;
        sh[threadIdx.x] = (i < NN) ? cnt[i] : 0;
        __syncthreads();
        for (int off = 1; off < 1024; off <<= 1) {
            int t = (threadIdx.x >= off) ? sh[threadIdx.x - off] : 0;
            __syncthreads();
            sh[threadIdx.x] += t;
            __syncthreads();
        }
        if (i < NN) rowptr[i + 1] = carry + sh[threadIdx.x];
        __syncthreads();
        if (threadIdx.x == 0) carry += sh[1023];
        __syncthreads();
    }
    if (threadIdx.x == 0) rowptr[0] = 0;
}

// scatter edges into CSR slots: edges[pos] = (col, val_bits)
__global__ void k_fill(const int* __restrict__ ei, const float* __restrict__ dis,
                       const int* __restrict__ rowptr, int* __restrict__ cursor,
                       int2* __restrict__ edges) {
    int e = blockIdx.x * blockDim.x + threadIdx.x;
    if (e >= NE) return;
    int r = ei[e], c = ei[NE + e];
    float v = dis[r] * dis[c];
    int pos = rowptr[r] + atomicAdd(&cursor[r], 1);
    edges[pos] = make_int2(c, __float_as_int(v));
}

// --- per-layer fused kernel --------------------------------------------------
// wave per row: sum = (A_hat x)[r]; xn = (1-b)xo + b*sum; acc += 0.5*xn + 0.5*al*xo
__global__ __launch_bounds__(256) void k_layer(const int* __restrict__ rowptr,
                                               const int2* __restrict__ edges,
                                               const float* __restrict__ xo,
                                               float* __restrict__ xn,
                                               float* __restrict__ acc,
                                               float b, float al) {
    int wave = threadIdx.x >> 6;
    int lane = threadIdx.x & 63;
    int r = blockIdx.x * 4 + wave;
    if (r >= NN) return;
    int beg = rowptr[r], end = rowptr[r + 1];
    int d2 = lane * 2;
    float2 sum = {0.f, 0.f};
    for (int p = beg; p < end; ++p) {
        int2 ev = edges[p];
        float v = __int_as_float(ev.y);
        const float2 xv = *reinterpret_cast<const float2*>(xo + (size_t)ev.x * DD + d2);
        sum.x += v * xv.x;
        sum.y += v * xv.y;
    }
    size_t i = (size_t)r * DD + d2;
    float2 o = *reinterpret_cast<const float2*>(xo + i);
    float2 n;
    n.x = (1.f - b) * o.x + b * sum.x;
    n.y = (1.f - b) * o.y + b * sum.y;
    float2 a = *reinterpret_cast<float2*>(acc + i);
    a.x += 0.5f * n.x + 0.5f * al * o.x;
    a.y += 0.5f * n.y + 0.5f * al * o.y;
    *reinterpret_cast<float2*>(xn + i) = n;
    *reinterpret_cast<float2*>(acc + i) = a;
}

// acc[nr] += coef * x[nc] over the 120 mirrored negative edges of this layer
__global__ void k_neg(const int* __restrict__ nl, const float* __restrict__ x,
                      float* __restrict__ acc, float coef) {
    int tid = blockIdx.x * blockDim.x + threadIdx.x;
    int e = tid >> 5;
    if (e >= 120) return;
    int d4 = (tid & 31) << 2;
    int r = nl[e];
    int c = (e < 60) ? nl[60 + e] : nl[e - 60];
    const float4 xv = *reinterpret_cast<const float4*>(x + (size_t)c * DD + d4);
    float* ap = acc + (size_t)r * DD + d4;
    atomicAdd(ap + 0, coef * xv.x);
    atomicAdd(ap + 1, coef * xv.y);
    atomicAdd(ap + 2, coef * xv.z);
    atomicAdd(ap + 3, coef * xv.w);
}

// out = ALPHA*feat + ((1-ALPHA)/16)*acc   (acc lives in out)
__global__ void k_final(const float* __restrict__ feat, float* __restrict__ out) {
    size_t i = ((size_t)blockIdx.x * blockDim.x + threadIdx.x) * 4;
    if (i >= (size_t)NN * DD) return;
    float4 f = *reinterpret_cast<const float4*>(feat + i);
    float4 a = *reinterpret_cast<float4*>(out + i);
    float4 o;
    const float s = 0.85f / 16.f;
    o.x = 0.15f * f.x + s * a.x;
    o.y = 0.15f * f.y + s * a.y;
    o.z = 0.15f * f.z + s * a.z;
    o.w = 0.15f * f.w + s * a.w;
    *reinterpret_cast<float4*>(out + i) = o;
}

extern "C" void kernel_launch(void* const* d_in, const int* in_sizes, int n_in,
                              void* d_out, int out_size, void* d_ws, size_t ws_size,
                              hipStream_t stream) {
    const float* feat = (const float*)d_in[0];
    const int* ei = (const int*)d_in[1];
    const int* negei = (const int*)d_in[2];
    float* out = (float*)d_out;

    float* x0 = (float*)d_ws;                        // NN*DD f32
    float* x1 = x0 + (size_t)NN * DD;                // NN*DD f32
    int2* edges = (int2*)(x1 + (size_t)NN * DD);     // NE int2
    int* rowptr = (int*)(edges + NE);                // NN+1
    int* deg = rowptr + (NN + 1);                    // NN (reused as cursor)
    float* dis = (float*)(deg + NN);                 // NN

    const size_t xbytes = (size_t)NN * DD * sizeof(float);

    hipMemsetAsync(deg, 0, NN * sizeof(int), stream);
    hipMemsetAsync(out, 0, xbytes, stream);
    hipMemcpyAsync(x0, feat, xbytes, hipMemcpyDeviceToDevice, stream);

    k_deg<<<(NE + 255) / 256, 256, 0, stream>>>(ei, deg);
    k_dis<<<(NN + 255) / 256, 256, 0, stream>>>(deg, dis);
    k_scan<<<1, 1024, 0, stream>>>(deg, rowptr);
    hipMemsetAsync(deg, 0, NN * sizeof(int), stream);   // deg -> cursor
    k_fill<<<(NE + 255) / 256, 256, 0, stream>>>(ei, dis, rowptr, deg, edges);

    const double c = 120.0 / 100000.0 + 2.0;
    double b = 1.0, bn = 1.0;
    float* xo = x0;
    float* xn = x1;
    const int pw_blocks = ((NN * DD / 4) + 255) / 256;
    for (int l = 0; l < NL; ++l) {
        float negcoef = (float)(-0.5 * bn / c);
        k_neg<<<(120 * 32 + 255) / 256, 256, 0, stream>>>(negei + l * 120, xo, out, negcoef);
        float al = (float)((1.0 - bn) + 2.0 * bn / c);
        k_layer<<<NN / 4, 256, 0, stream>>>(rowptr, edges, xo, xn, out, (float)b, al);
        float* t = xo; xo = xn; xn = t;
        b *= 0.9; bn *= 0.5;
    }
    k_final<<<pw_blocks, 256, 0, stream>>>(feat, out);
}

// Round 3
// 1295.252 us; speedup vs baseline: 13.0422x; 1.2746x over previous
//
#include <hip/hip_runtime.h>

#define NN 100000
#define NE 600000
#define DD 128
#define NL 16
#define SCAN_B 1024
#define SCAN_NB ((NN + SCAN_B - 1) / SCAN_B)   // 98

// --- CSR build ---------------------------------------------------------------

__global__ void k_deg(const int* __restrict__ ei, int* __restrict__ deg) {
    int e = blockIdx.x * blockDim.x + threadIdx.x;
    if (e < NE) atomicAdd(&deg[ei[e]], 1);
}

__global__ void k_dis(const int* __restrict__ deg, float* __restrict__ dis) {
    int i = blockIdx.x * blockDim.x + threadIdx.x;
    if (i >= NN) return;
    int d = deg[i];
    dis[i] = d > 0 ? rsqrtf((float)d) : 0.f;
}

// per-block sums of deg chunks
__global__ void k_bsum(const int* __restrict__ cnt, int* __restrict__ bsum) {
    __shared__ int sh[SCAN_B];
    int i = blockIdx.x * SCAN_B + threadIdx.x;
    sh[threadIdx.x] = (i < NN) ? cnt[i] : 0;
    __syncthreads();
    for (int off = SCAN_B / 2; off > 0; off >>= 1) {
        if (threadIdx.x < off) sh[threadIdx.x] += sh[threadIdx.x + off];
        __syncthreads();
    }
    if (threadIdx.x == 0) bsum[blockIdx.x] = sh[0];
}

// exclusive scan of the 98 block sums (one wave, serial — trivial size)
__global__ void k_bscan(int* __restrict__ bsum) {
    if (threadIdx.x == 0) {
        int run = 0;
        for (int i = 0; i < SCAN_NB; ++i) { int v = bsum[i]; bsum[i] = run; run += v; }
    }
}

// per-chunk inclusive LDS scan + block offset -> rowptr
__global__ void k_scan2(const int* __restrict__ cnt, const int* __restrict__ bsum,
                        int* __restrict__ rowptr) {
    __shared__ int sh[SCAN_B];
    int i = blockIdx.x * SCAN_B + threadIdx.x;
    sh[threadIdx.x] = (i < NN) ? cnt[i] : 0;
    __syncthreads();
    for (int off = 1; off < SCAN_B; off <<= 1) {
        int t = (threadIdx.x >= off) ? sh[threadIdx.x - off] : 0;
        __syncthreads();
        sh[threadIdx.x] += t;
        __syncthreads();
    }
    if (i < NN) rowptr[i + 1] = bsum[blockIdx.x] + sh[threadIdx.x];
    if (blockIdx.x == 0 && threadIdx.x == 0) rowptr[0] = 0;
}

// scatter edges into CSR slots: edges[pos] = (col, val_bits)
__global__ void k_fill(const int* __restrict__ ei, const float* __restrict__ dis,
                       const int* __restrict__ rowptr, int* __restrict__ cursor,
                       int2* __restrict__ edges) {
    int e = blockIdx.x * blockDim.x + threadIdx.x;
    if (e >= NE) return;
    int r = ei[e], c = ei[NE + e];
    float v = dis[r] * dis[c];
    int pos = rowptr[r] + atomicAdd(&cursor[r], 1);
    edges[pos] = make_int2(c, __float_as_int(v));
}

// --- per-layer fused kernel --------------------------------------------------
// wave per row: sum = (A_hat x)[r]; xn = (1-b)xo + b*sum; acc += 0.5*xn + 0.5*al*xo
__global__ __launch_bounds__(256) void k_layer(const int* __restrict__ rowptr,
                                               const int2* __restrict__ edges,
                                               const float* __restrict__ xo,
                                               float* __restrict__ xn,
                                               float* __restrict__ acc,
                                               float b, float al) {
    int wave = threadIdx.x >> 6;
    int lane = threadIdx.x & 63;
    int r = blockIdx.x * 4 + wave;
    if (r >= NN) return;
    int beg = rowptr[r], end = rowptr[r + 1];
    int d2 = lane * 2;
    float2 sum = {0.f, 0.f};
    int p = beg;
    for (; p + 1 < end; p += 2) {
        int2 e0 = edges[p];
        int2 e1 = edges[p + 1];
        float v0 = __int_as_float(e0.y);
        float v1 = __int_as_float(e1.y);
        const float2 x0 = *reinterpret_cast<const float2*>(xo + (size_t)e0.x * DD + d2);
        const float2 x1 = *reinterpret_cast<const float2*>(xo + (size_t)e1.x * DD + d2);
        sum.x += v0 * x0.x + v1 * x1.x;
        sum.y += v0 * x0.y + v1 * x1.y;
    }
    if (p < end) {
        int2 ev = edges[p];
        float v = __int_as_float(ev.y);
        const float2 xv = *reinterpret_cast<const float2*>(xo + (size_t)ev.x * DD + d2);
        sum.x += v * xv.x;
        sum.y += v * xv.y;
    }
    size_t i = (size_t)r * DD + d2;
    float2 o = *reinterpret_cast<const float2*>(xo + i);
    float2 n;
    n.x = (1.f - b) * o.x + b * sum.x;
    n.y = (1.f - b) * o.y + b * sum.y;
    float2 a = *reinterpret_cast<float2*>(acc + i);
    a.x += 0.5f * n.x + 0.5f * al * o.x;
    a.y += 0.5f * n.y + 0.5f * al * o.y;
    *reinterpret_cast<float2*>(xn + i) = n;
    *reinterpret_cast<float2*>(acc + i) = a;
}

// acc[nr] += coef * x[nc] over the 120 mirrored negative edges of this layer
__global__ void k_neg(const int* __restrict__ nl, const float* __restrict__ x,
                      float* __restrict__ acc, float coef) {
    int tid = blockIdx.x * blockDim.x + threadIdx.x;
    int e = tid >> 5;
    if (e >= 120) return;
    int d4 = (tid & 31) << 2;
    int r = nl[e];
    int c = (e < 60) ? nl[60 + e] : nl[e - 60];
    const float4 xv = *reinterpret_cast<const float4*>(x + (size_t)c * DD + d4);
    float* ap = acc + (size_t)r * DD + d4;
    atomicAdd(ap + 0, coef * xv.x);
    atomicAdd(ap + 1, coef * xv.y);
    atomicAdd(ap + 2, coef * xv.z);
    atomicAdd(ap + 3, coef * xv.w);
}

// out = ALPHA*feat + ((1-ALPHA)/16)*acc   (acc lives in out)
__global__ void k_final(const float* __restrict__ feat, float* __restrict__ out) {
    size_t i = ((size_t)blockIdx.x * blockDim.x + threadIdx.x) * 4;
    if (i >= (size_t)NN * DD) return;
    float4 f = *reinterpret_cast<const float4*>(feat + i);
    float4 a = *reinterpret_cast<float4*>(out + i);
    float4 o;
    const float s = 0.85f / 16.f;
    o.x = 0.15f * f.x + s * a.x;
    o.y = 0.15f * f.y + s * a.y;
    o.z = 0.15f * f.z + s * a.z;
    o.w = 0.15f * f.w + s * a.w;
    *reinterpret_cast<float4*>(out + i) = o;
}

extern "C" void kernel_launch(void* const* d_in, const int* in_sizes, int n_in,
                              void* d_out, int out_size, void* d_ws, size_t ws_size,
                              hipStream_t stream) {
    const float* feat = (const float*)d_in[0];
    const int* ei = (const int*)d_in[1];
    const int* negei = (const int*)d_in[2];
    float* out = (float*)d_out;

    float* x0 = (float*)d_ws;                        // NN*DD f32
    float* x1 = x0 + (size_t)NN * DD;                // NN*DD f32
    int2* edges = (int2*)(x1 + (size_t)NN * DD);     // NE int2
    int* rowptr = (int*)(edges + NE);                // NN+1
    int* deg = rowptr + (NN + 1);                    // NN (reused as cursor)
    float* dis = (float*)(deg + NN);                 // NN
    int* bsum = (int*)(dis + NN);                    // SCAN_NB

    const size_t xbytes = (size_t)NN * DD * sizeof(float);

    hipMemsetAsync(deg, 0, NN * sizeof(int), stream);
    hipMemsetAsync(out, 0, xbytes, stream);
    hipMemcpyAsync(x0, feat, xbytes, hipMemcpyDeviceToDevice, stream);

    k_deg<<<(NE + 255) / 256, 256, 0, stream>>>(ei, deg);
    k_dis<<<(NN + 255) / 256, 256, 0, stream>>>(deg, dis);
    k_bsum<<<SCAN_NB, SCAN_B, 0, stream>>>(deg, bsum);
    k_bscan<<<1, 64, 0, stream>>>(bsum);
    k_scan2<<<SCAN_NB, SCAN_B, 0, stream>>>(deg, bsum, rowptr);
    hipMemsetAsync(deg, 0, NN * sizeof(int), stream);   // deg -> cursor
    k_fill<<<(NE + 255) / 256, 256, 0, stream>>>(ei, dis, rowptr, deg, edges);

    const double c = 120.0 / 100000.0 + 2.0;
    double b = 1.0, bn = 1.0;
    float* xo = x0;
    float* xn = x1;
    const int pw_blocks = ((NN * DD / 4) + 255) / 256;
    for (int l = 0; l < NL; ++l) {
        float negcoef = (float)(-0.5 * bn / c);
        k_neg<<<(120 * 32 + 255) / 256, 256, 0, stream>>>(negei + l * 120, xo, out, negcoef);
        float al = (float)((1.0 - bn) + 2.0 * bn / c);
        k_layer<<<(NN + 3) / 4, 256, 0, stream>>>(rowptr, edges, xo, xn, out, (float)b, al);
        float* t = xo; xo = xn; xn = t;
        b *= 0.9; bn *= 0.5;
    }
    k_final<<<pw_blocks, 256, 0, stream>>>(feat, out);
}